// Round 5
// baseline (6335.664 us; speedup 1.0000x reference)
//
#include <hip/hip_runtime.h>
#include <hip/hip_bf16.h>
#include <hip/hip_fp16.h>

// ---------------------------------------------------------------------------
// 4-layer LSTM (H=1024, B=64, T=256) + FC, persistent pipelined kernel.
// R9: R8 (per-producer flags, wave-parallel polls - proven -230us) with the
//     fresh-mode GEMM inner loop rebuilt as an explicit 6-deep software
//     pipeline. R8's unroll-2 exposed ~8 IF$ round-trips per GEMM phase
//     (a-operand h loads, ~900-1500cy each, covered by only 77cy of MFMA)
//     with 1 wave/SIMD -> no TLP to hide them. The prefetch ring (pa/pb
//     [6][4], fully unrolled, compile-time indices only) issues loads 6
//     iterations ahead -> ~2 exposed round-trips. Registers ~320 of 512;
//     WRITE_SIZE is the spill sentinel (must stay 133120 KB).
//     Fallback (!fresh) path unchanged (sc loads, unroll 2).
// ---------------------------------------------------------------------------

#define H      1024
#define BATCH  64
#define T      256
#define RINGN  8

typedef _Float16 f16x8 __attribute__((ext_vector_type(8)));
typedef _Float16 f16x4 __attribute__((ext_vector_type(4)));
typedef float    f32x4 __attribute__((ext_vector_type(4)));

// ws layout (bytes)
#define WPACK_HH_SZ  (4ull*64*32*4*64*8*2)           // 33554432: [l][wg][ks][nt][lane][8] f16
#define WPACK_IH_SZ  (3ull*64*32*4*64*8*2)           // 25165824
#define HRING_OFF    (WPACK_HH_SZ + WPACK_IH_SZ)     // 58720256
#define SLOT_ELEMS   65536                           // per (l,slot): 64 batch x 1024 units f16
#define SLOT_BYTES   131072ull
#define CNT_INTS     (4*257*16)                      // flag/cnt2 region, 64B-padded entries
#define CNT_BYTES    ((unsigned long long)CNT_INTS*4)

__host__ __device__ __forceinline__ unsigned long long ring_bytes(int nslot) {
  return 4ull*(unsigned)nslot*SLOT_BYTES;
}
__device__ __forceinline__ int cidx(int l, int s) { return (l*257 + s)*16; }
// per-producer flag index: one 64B line per (layer, wg-block)
__device__ __forceinline__ int fidx(int l, int w) { return (l*64 + w)*16; }

// fresh mode: bit-reversed slot index kills any sequential-prefetch adjacency
__device__ __forceinline__ int aslot(int s, int fresh) {
  if (!fresh) return s & 7;
  return (s >= 256) ? 256 : (int)(__brev((unsigned)s) >> 24);
}

__device__ __forceinline__ void wait_eq64(int* p) {
  int it = 0;
  while (__hip_atomic_load(p, __ATOMIC_RELAXED, __HIP_MEMORY_SCOPE_AGENT) < 64) {
    __builtin_amdgcn_s_sleep(1);
    if (++it > 100000000) break;   // failsafe: never hang the harness
  }
}

// per-lane spin: lane waits until *p >= tgt (monotone flag)
__device__ __forceinline__ void wait_ge(const int* p, int tgt) {
  int it = 0;
  while (__hip_atomic_load(p, __ATOMIC_RELAXED, __HIP_MEMORY_SCOPE_AGENT) < tgt) {
    __builtin_amdgcn_s_sleep(1);
    if (++it > 100000000) break;   // failsafe: never hang the harness
  }
}

__device__ __forceinline__ f16x8 load_h8_sc(const _Float16* p) {
  const unsigned long long* q = (const unsigned long long*)p;
  unsigned long long lo = __hip_atomic_load(q,     __ATOMIC_RELAXED, __HIP_MEMORY_SCOPE_AGENT);
  unsigned long long hi = __hip_atomic_load(q + 1, __ATOMIC_RELAXED, __HIP_MEMORY_SCOPE_AGENT);
  union { unsigned long long u[2]; f16x8 v; } c;
  c.u[0] = lo; c.u[1] = hi;
  return c.v;
}

// deep-pipelined GEMM segment: NK kbody iterations, DEPTH-deep prefetch ring.
// All loop indices compile-time (full unroll) so pa/pb stay in registers.
template <int NK, bool BLDS>
__device__ __forceinline__ void gemm_pipe(const _Float16* __restrict__ asrc,
                                          const _Float16* __restrict__ bsrc,
                                          int ks0, int quad, int m_row, int lane,
                                          f32x4 (&acc)[4][4])
{
  constexpr int DEPTH = (NK < 6) ? NK : 6;
  f16x8 pa[DEPTH][4], pb[DEPTH][4];
  auto issue = [&](int slot, int i) {
    const int ks = ks0 + i;
    const int kb = ks*32 + quad*8;
    #pragma unroll
    for (int mt = 0; mt < 4; mt++)
      pa[slot][mt] = *(const f16x8*)(asrc + (size_t)(mt*16 + m_row)*1024 + kb);
    #pragma unroll
    for (int nt = 0; nt < 4; nt++)
      pb[slot][nt] = *(const f16x8*)(bsrc + ((size_t)(ks*4 + nt)*64 + lane)*8);
    (void)BLDS;
  };
  #pragma unroll
  for (int i = 0; i < DEPTH; i++) issue(i, i);
  #pragma unroll
  for (int i = 0; i < NK; i++) {
    const int slot = i % DEPTH;
    #pragma unroll
    for (int mt = 0; mt < 4; mt++)
      #pragma unroll
      for (int nt = 0; nt < 4; nt++)
        acc[mt][nt] = __builtin_amdgcn_mfma_f32_16x16x32_f16(pa[slot][mt], pb[slot][nt],
                                                             acc[mt][nt], 0, 0, 0);
    if (i + DEPTH < NK) issue(slot, i + DEPTH);
  }
}

// --- pack weights fp32 -> fp16 MFMA-fragment layout; zero h ring slot 0; preset flags=0
__global__ void pack_kernel(const float* __restrict__ w_ih_rest,
                            const float* __restrict__ w_hh,
                            char* __restrict__ ws, int nslot)
{
  const long long NS_HH = 4ll*64*32*4*64;   // 2097152
  const long long NS_IH = 3ll*64*32*4*64;   // 1572864
  const long long NS_HZ = 4ll*8192;         // uint4 slots to zero slot-0 of each layer ring
  const long long NTOT  = NS_HH + NS_IH + NS_HZ + 256;
  _Float16* whh_dst = (_Float16*)ws;
  _Float16* wih_dst = (_Float16*)(ws + WPACK_HH_SZ);
  int* cnt = (int*)(ws + HRING_OFF + ring_bytes(nslot));
  for (long long i = blockIdx.x*(long long)blockDim.x + threadIdx.x; i < NTOT;
       i += (long long)gridDim.x*blockDim.x) {
    if (i < NS_HH + NS_IH) {
      const bool is_hh = (i < NS_HH);
      long long slot = is_hh ? i : (i - NS_HH);
      long long j = slot;
      int lane = (int)(j & 63); j >>= 6;
      int nt   = (int)(j & 3);  j >>= 2;
      int ks   = (int)(j & 31); j >>= 5;
      int wg   = (int)(j & 63); j >>= 6;
      int l    = (int)j;
      int row = nt*1024 + wg*16 + (lane & 15);      // global gate row (nt = gate: i,f,g,o)
      int col = ks*32 + (lane >> 4)*8;
      const float* src = (is_hh ? w_hh : w_ih_rest) + ((long long)l*4096 + row)*1024 + col;
      f16x8 v;
      #pragma unroll
      for (int e = 0; e < 8; e++) v[e] = (_Float16)src[e];
      *(f16x8*)((is_hh ? whh_dst : wih_dst) + slot*8) = v;
    } else if (i < NS_HH + NS_IH + NS_HZ) {
      long long j = i - (NS_HH + NS_IH);
      long long l = j >> 13;            // /8192
      long long off = j & 8191;
      uint4 z = make_uint4(0,0,0,0);
      ((uint4*)(ws + HRING_OFF))[(l*(long long)nslot)*8192 + off] = z;  // zero h[l][slot0]
    } else {
      int k = (int)(i - (NS_HH + NS_IH + NS_HZ));   // 0..255 = l*64+wg
      cnt[k*16] = 0;                                // flag: "step 0 published"
    }
  }
}

__global__ __launch_bounds__(256, 1) void lstm_main(
    const float* __restrict__ x,
    const float* __restrict__ wih0,
    const float* __restrict__ bih,
    const float* __restrict__ bhh,
    char* __restrict__ ws, int nslot, int fresh)
{
  // one-time agent acquire: emits buffer_inv sc1 -> kills stale L1/L2 lines
  // from previous graph replays / poison-memset. Required for fresh-mode
  // plain consumer loads; harmless otherwise.
  __builtin_amdgcn_fence(__ATOMIC_ACQUIRE, "agent");

  extern __shared__ char lds[];
  _Float16* whh_lds = (_Float16*)lds;              // 131072 B, frag layout [ks][nt][lane][8]
  _Float16* buf0    = (_Float16*)(lds + 131072);   // 8192 B partial-sum frags (waves 0+2)
  _Float16* buf1    = (_Float16*)(lds + 139264);   // 8192 B partial-sum frags (waves 1+3)

  const int l   = blockIdx.x >> 6;
  const int wg  = blockIdx.x & 63;
  const int tid = threadIdx.x;
  const int wave = tid >> 6;
  const int lane = tid & 63;

  const _Float16* wpack_hh = (const _Float16*)ws + (size_t)(l*64 + wg)*65536;
  const _Float16* wpack_ih = (l > 0)
      ? (const _Float16*)(ws + WPACK_HH_SZ) + (size_t)((l-1)*64 + wg)*65536
      : wpack_hh;  // unused for l==0
  _Float16* hring = (_Float16*)(ws + HRING_OFF);
  int* cnt  = (int*)(ws + HRING_OFF + ring_bytes(nslot));   // per-producer flags
  int* cnt2 = cnt + CNT_INTS;                               // fallback backpressure (atomic)

  // stage w_hh slice into LDS (one-time; wpack is immutable during this kernel)
  {
    const uint4* src = (const uint4*)wpack_hh;
    uint4* dst = (uint4*)whh_lds;
    for (int i = tid; i < 8192; i += 256) dst[i] = src[i];
  }

  // elementwise ownership: thread -> (batch b_ew, 4 consecutive hidden units u0..u0+3)
  const int b_ew = tid >> 2;
  const int u0   = (tid & 3) * 4;
  float cst[4] = {0.f, 0.f, 0.f, 0.f};
  float bias[4][4];            // [item][gate]
  float wx0[4][4], wx1[4][4];  // layer-0 input weights (K=2 handled in VALU)
  #pragma unroll
  for (int ii = 0; ii < 4; ii++) {
    #pragma unroll
    for (int g = 0; g < 4; g++) {
      int row = g*1024 + wg*16 + u0 + ii;
      bias[ii][g] = bih[l*4096 + row] + bhh[l*4096 + row];
      if (l == 0) { wx0[ii][g] = wih0[row*2]; wx1[ii][g] = wih0[row*2 + 1]; }
      else        { wx0[ii][g] = 0.f;         wx1[ii][g] = 0.f; }
    }
  }
  __syncthreads();

  const int m_row = lane & 15, quad = lane >> 4;

  for (int s = 1; s <= T; s++) {
    // wave-parallel waits: lane i spins on producer i's flag (64 independent
    // 64B lines; no RMW anywhere). Wave 0: own layer at >= s-1 (lockstep +
    // own h). Wave 1: layer below at >= s (input). tid 128: fallback ring
    // backpressure (atomic path, unused in fresh mode).
    if (wave == 0) {
      wait_ge(cnt + fidx(l, lane), s - 1);
    } else if (wave == 1) {
      if (l > 0) wait_ge(cnt + fidx(l - 1, lane), s);
    } else if (tid == 128) {
      if (!fresh && l < 3 && s > RINGN) wait_eq64(&cnt2[cidx(l, s-RINGN)]);
    }
    __syncthreads();

    // A source: for l>0 waves 0-1 consume h_below[s] (with w_ih), waves 2-3 h_own[s-1] (w_hh)
    const _Float16* asrc = (l > 0 && wave < 2)
        ? hring + ((size_t)(l-1)*nslot + aslot(s,   fresh))*SLOT_ELEMS
        : hring + ((size_t)l*nslot     + aslot(s-1, fresh))*SLOT_ELEMS;

    f32x4 acc[4][4];
    #pragma unroll
    for (int mt = 0; mt < 4; mt++)
      #pragma unroll
      for (int nt = 0; nt < 4; nt++) acc[mt][nt] = (f32x4){0.f, 0.f, 0.f, 0.f};

    if (fresh) {
      // deep-pipelined plain-load path
      if (l == 0) {
        gemm_pipe<8,  true >(asrc, whh_lds,  wave*8,      quad, m_row, lane, acc);
      } else if (wave < 2) {
        gemm_pipe<16, false>(asrc, wpack_ih, wave*16,     quad, m_row, lane, acc);
      } else {
        gemm_pipe<16, true >(asrc, whh_lds,  (wave-2)*16, quad, m_row, lane, acc);
      }
    } else {
      // fallback: sc loads, unroll 2 (ring reuse mode)
      auto kbody = [&](int ks, bool from_lds) {
        const int kb = ks*32 + quad*8;
        f16x8 a[4], bb[4];
        #pragma unroll
        for (int mt = 0; mt < 4; mt++) {
          const _Float16* ap = asrc + (size_t)(mt*16 + m_row)*1024 + kb;
          a[mt] = load_h8_sc(ap);
        }
        if (from_lds) {
          #pragma unroll
          for (int nt = 0; nt < 4; nt++)
            bb[nt] = *(const f16x8*)(whh_lds + ((ks*4 + nt)*64 + lane)*8);
        } else {
          #pragma unroll
          for (int nt = 0; nt < 4; nt++)
            bb[nt] = *(const f16x8*)(wpack_ih + ((size_t)(ks*4 + nt)*64 + lane)*8);
        }
        #pragma unroll
        for (int mt = 0; mt < 4; mt++)
          #pragma unroll
          for (int nt = 0; nt < 4; nt++)
            acc[mt][nt] = __builtin_amdgcn_mfma_f32_16x16x32_f16(a[mt], bb[nt], acc[mt][nt], 0, 0, 0);
      };
      if (l == 0) {
        #pragma unroll 2
        for (int i = 0; i < 8; i++) kbody(wave*8 + i, true);
      } else if (wave < 2) {
        #pragma unroll 2
        for (int i = 0; i < 16; i++) kbody(wave*16 + i, false);
      } else {
        #pragma unroll 2
        for (int i = 0; i < 16; i++) kbody((wave-2)*16 + i, true);
      }
    }

    // combine 4 wave-partials -> buf0 (w0+w2), buf1 (w1+w3), fp16 frags
    _Float16* mybuf = ((wave & 1) == 0) ? buf0 : buf1;
    if (wave >= 2) {
      #pragma unroll
      for (int mt = 0; mt < 4; mt++)
        #pragma unroll
        for (int nt = 0; nt < 4; nt++) {
          f16x4 v;
          #pragma unroll
          for (int e = 0; e < 4; e++) v[e] = (_Float16)acc[mt][nt][e];
          *(f16x4*)(mybuf + ((mt*4 + nt)*64 + lane)*4) = v;
        }
    }
    __syncthreads();   // drains vmcnt: all h reads physically complete
    if (wave < 2) {
      #pragma unroll
      for (int mt = 0; mt < 4; mt++)
        #pragma unroll
        for (int nt = 0; nt < 4; nt++) {
          f16x4 p = *(f16x4*)(mybuf + ((mt*4 + nt)*64 + lane)*4);
          f16x4 v;
          #pragma unroll
          for (int e = 0; e < 4; e++) v[e] = (_Float16)(acc[mt][nt][e] + (float)p[e]);
          *(f16x4*)(mybuf + ((mt*4 + nt)*64 + lane)*4) = v;
        }
    }
    // ring backpressure signal only needed when slots are reused (fallback mode)
    if (!fresh && tid == 0 && l > 0)
      __hip_atomic_fetch_add(&cnt2[cidx(l-1, s)], 1, __ATOMIC_RELAXED, __HIP_MEMORY_SCOPE_AGENT);
    __syncthreads();

    // elementwise gates -> c,h  (fp32)
    {
      const int mt = b_ew >> 4, q = (b_ew & 15) >> 2, reg = b_ew & 3;
      float xs0 = 0.f, xs1 = 0.f;
      if (l == 0) {
        xs0 = x[((size_t)b_ew*T + (s-1))*2];
        xs1 = x[((size_t)b_ew*T + (s-1))*2 + 1];
      }
      f16x4 hv;
      #pragma unroll
      for (int ii = 0; ii < 4; ii++) {
        const int u = u0 + ii;
        float pre[4];
        #pragma unroll
        for (int g = 0; g < 4; g++) {
          int idx = ((mt*4 + g)*64 + (u + 16*q))*4 + reg;
          pre[g] = (float)buf0[idx] + (float)buf1[idx] + bias[ii][g]
                 + wx0[ii][g]*xs0 + wx1[ii][g]*xs1;
        }
        float ig = 1.f/(1.f + __expf(-pre[0]));
        float fg = 1.f/(1.f + __expf(-pre[1]));
        float gg = 2.f/(1.f + __expf(-2.f*pre[2])) - 1.f;
        float og = 1.f/(1.f + __expf(-pre[3]));
        float c  = fg*cst[ii] + ig*gg;
        cst[ii] = c;
        float th = 2.f/(1.f + __expf(-2.f*c)) - 1.f;
        hv[ii] = (_Float16)(og*th);
      }
      _Float16* hdst = hring + ((size_t)l*nslot + aslot(s, fresh))*SLOT_ELEMS
                     + (size_t)b_ew*1024 + wg*16 + u0;
      union { f16x4 v; unsigned long long u; } cv; cv.v = hv;
      // sc write-through: IF$ (coherence point) holds the authoritative copy
      __hip_atomic_store((unsigned long long*)hdst, cv.u,
                         __ATOMIC_RELAXED, __HIP_MEMORY_SCOPE_AGENT);
    }
    __syncthreads();   // drains vmcnt: h stores acked at coherence point before flag
    if (tid == 0)      // plain sc store publish: no RMW, per-producer line
      __hip_atomic_store(cnt + fidx(l, wg), s,
                         __ATOMIC_RELAXED, __HIP_MEMORY_SCOPE_AGENT);
  }
}

__global__ void fc_kernel(const char* __restrict__ ws,
                          const float* __restrict__ fcw,
                          const float* __restrict__ fcb,
                          float* __restrict__ out, int nslot, int fresh)
{
  const _Float16* h3 = (const _Float16*)(ws + HRING_OFF)
                     + ((size_t)3*nslot + aslot(T, fresh))*SLOT_ELEMS;  // layer 3, t=256
  __shared__ float red[256];
  const int tid = threadIdx.x;
  const int b = tid >> 2, p = tid & 3;
  float sum = 0.f;
  for (int j = p*256; j < p*256 + 256; j++)
    sum += fcw[j] * (float)h3[(size_t)b*1024 + j];
  red[tid] = sum;
  __syncthreads();
  if (p == 0)
    out[b] = red[tid] + red[tid+1] + red[tid+2] + red[tid+3] + fcb[0];
}

extern "C" void kernel_launch(void* const* d_in, const int* in_sizes, int n_in,
                              void* d_out, int out_size, void* d_ws, size_t ws_size,
                              hipStream_t stream)
{
  const float* x    = (const float*)d_in[0];
  const float* wih0 = (const float*)d_in[1];
  const float* wihr = (const float*)d_in[2];
  const float* whh  = (const float*)d_in[3];
  const float* bih  = (const float*)d_in[4];
  const float* bhh  = (const float*)d_in[5];
  const float* fcw  = (const float*)d_in[6];
  const float* fcb  = (const float*)d_in[7];
  float* out = (float*)d_out;
  char* ws = (char*)d_ws;
  (void)in_sizes; (void)n_in; (void)out_size;

  const unsigned long long ws_big   = HRING_OFF + ring_bytes(257) + 2*CNT_BYTES; // ~193.6 MB
  const unsigned long long ws_small = HRING_OFF + ring_bytes(8)   + 2*CNT_BYTES; // ~63 MB
  if (ws_size < ws_small) return;
  const int fresh = (ws_size >= ws_big) ? 1 : 0;
  const int nslot = fresh ? 257 : 8;

  // opt-in to 147456 B dynamic LDS (host-side, idempotent, capture-safe)
  hipFuncSetAttribute(reinterpret_cast<const void*>(lstm_main),
                      hipFuncAttributeMaxDynamicSharedMemorySize, 147456);

  hipMemsetAsync(ws + HRING_OFF + ring_bytes(nslot), 0, (size_t)(2*CNT_BYTES), stream);
  pack_kernel<<<512, 256, 0, stream>>>(wihr, whh, ws, nslot);
  lstm_main<<<256, 256, 147456, stream>>>(x, wih0, bih, bhh, ws, nslot, fresh);
  fc_kernel<<<1, 256, 0, stream>>>(ws, fcw, fcb, out, nslot, fresh);
}

// Round 6
// 3855.717 us; speedup vs baseline: 1.6432x; 1.6432x over previous
//
#include <hip/hip_runtime.h>
#include <hip/hip_bf16.h>
#include <hip/hip_fp16.h>

// ---------------------------------------------------------------------------
// 4-layer LSTM (H=1024, B=64, T=256) + FC, persistent pipelined kernel.
// R10: R8 verbatim (per-producer flags + wave-parallel polls, specialized
//      waves, LDS w_hh, f16 partials, fresh bit-reversed ring) with ONE
//      change: fresh-mode GEMM loops go unroll 2 -> unroll 4.
//      R9's explicit 6-deep ring failed (allocator capped at 248 VGPR ->
//      schedule collapse, +64% dur); this expresses the same intent (halve
//      exposed load round-trips: 8 -> 4 per 16-kbody phase) in the form the
//      compiler preserves: wider unroll, direct LDS derefs, no forced-live
//      arrays. Transient regs ~230-260. WRITE_SIZE=133120 is the spill
//      sentinel. Fallback (!fresh) path unchanged.
// ---------------------------------------------------------------------------

#define H      1024
#define BATCH  64
#define T      256
#define RINGN  8

typedef _Float16 f16x8 __attribute__((ext_vector_type(8)));
typedef _Float16 f16x4 __attribute__((ext_vector_type(4)));
typedef float    f32x4 __attribute__((ext_vector_type(4)));

// ws layout (bytes)
#define WPACK_HH_SZ  (4ull*64*32*4*64*8*2)           // 33554432: [l][wg][ks][nt][lane][8] f16
#define WPACK_IH_SZ  (3ull*64*32*4*64*8*2)           // 25165824
#define HRING_OFF    (WPACK_HH_SZ + WPACK_IH_SZ)     // 58720256
#define SLOT_ELEMS   65536                           // per (l,slot): 64 batch x 1024 units f16
#define SLOT_BYTES   131072ull
#define CNT_INTS     (4*257*16)                      // flag/cnt2 region, 64B-padded entries
#define CNT_BYTES    ((unsigned long long)CNT_INTS*4)

__host__ __device__ __forceinline__ unsigned long long ring_bytes(int nslot) {
  return 4ull*(unsigned)nslot*SLOT_BYTES;
}
__device__ __forceinline__ int cidx(int l, int s) { return (l*257 + s)*16; }
// per-producer flag index: one 64B line per (layer, wg-block)
__device__ __forceinline__ int fidx(int l, int w) { return (l*64 + w)*16; }

// fresh mode: bit-reversed slot index kills any sequential-prefetch adjacency
__device__ __forceinline__ int aslot(int s, int fresh) {
  if (!fresh) return s & 7;
  return (s >= 256) ? 256 : (int)(__brev((unsigned)s) >> 24);
}

__device__ __forceinline__ void wait_eq64(int* p) {
  int it = 0;
  while (__hip_atomic_load(p, __ATOMIC_RELAXED, __HIP_MEMORY_SCOPE_AGENT) < 64) {
    __builtin_amdgcn_s_sleep(1);
    if (++it > 100000000) break;   // failsafe: never hang the harness
  }
}

// per-lane spin: lane waits until *p >= tgt (monotone flag)
__device__ __forceinline__ void wait_ge(const int* p, int tgt) {
  int it = 0;
  while (__hip_atomic_load(p, __ATOMIC_RELAXED, __HIP_MEMORY_SCOPE_AGENT) < tgt) {
    __builtin_amdgcn_s_sleep(1);
    if (++it > 100000000) break;   // failsafe: never hang the harness
  }
}

__device__ __forceinline__ f16x8 load_h8_sc(const _Float16* p) {
  const unsigned long long* q = (const unsigned long long*)p;
  unsigned long long lo = __hip_atomic_load(q,     __ATOMIC_RELAXED, __HIP_MEMORY_SCOPE_AGENT);
  unsigned long long hi = __hip_atomic_load(q + 1, __ATOMIC_RELAXED, __HIP_MEMORY_SCOPE_AGENT);
  union { unsigned long long u[2]; f16x8 v; } c;
  c.u[0] = lo; c.u[1] = hi;
  return c.v;
}

// --- pack weights fp32 -> fp16 MFMA-fragment layout; zero h ring slot 0; preset flags=0
__global__ void pack_kernel(const float* __restrict__ w_ih_rest,
                            const float* __restrict__ w_hh,
                            char* __restrict__ ws, int nslot)
{
  const long long NS_HH = 4ll*64*32*4*64;   // 2097152
  const long long NS_IH = 3ll*64*32*4*64;   // 1572864
  const long long NS_HZ = 4ll*8192;         // uint4 slots to zero slot-0 of each layer ring
  const long long NTOT  = NS_HH + NS_IH + NS_HZ + 256;
  _Float16* whh_dst = (_Float16*)ws;
  _Float16* wih_dst = (_Float16*)(ws + WPACK_HH_SZ);
  int* cnt = (int*)(ws + HRING_OFF + ring_bytes(nslot));
  for (long long i = blockIdx.x*(long long)blockDim.x + threadIdx.x; i < NTOT;
       i += (long long)gridDim.x*blockDim.x) {
    if (i < NS_HH + NS_IH) {
      const bool is_hh = (i < NS_HH);
      long long slot = is_hh ? i : (i - NS_HH);
      long long j = slot;
      int lane = (int)(j & 63); j >>= 6;
      int nt   = (int)(j & 3);  j >>= 2;
      int ks   = (int)(j & 31); j >>= 5;
      int wg   = (int)(j & 63); j >>= 6;
      int l    = (int)j;
      int row = nt*1024 + wg*16 + (lane & 15);      // global gate row (nt = gate: i,f,g,o)
      int col = ks*32 + (lane >> 4)*8;
      const float* src = (is_hh ? w_hh : w_ih_rest) + ((long long)l*4096 + row)*1024 + col;
      f16x8 v;
      #pragma unroll
      for (int e = 0; e < 8; e++) v[e] = (_Float16)src[e];
      *(f16x8*)((is_hh ? whh_dst : wih_dst) + slot*8) = v;
    } else if (i < NS_HH + NS_IH + NS_HZ) {
      long long j = i - (NS_HH + NS_IH);
      long long l = j >> 13;            // /8192
      long long off = j & 8191;
      uint4 z = make_uint4(0,0,0,0);
      ((uint4*)(ws + HRING_OFF))[(l*(long long)nslot)*8192 + off] = z;  // zero h[l][slot0]
    } else {
      int k = (int)(i - (NS_HH + NS_IH + NS_HZ));   // 0..255 = l*64+wg
      cnt[k*16] = 0;                                // flag: "step 0 published"
    }
  }
}

__global__ __launch_bounds__(256, 1) void lstm_main(
    const float* __restrict__ x,
    const float* __restrict__ wih0,
    const float* __restrict__ bih,
    const float* __restrict__ bhh,
    char* __restrict__ ws, int nslot, int fresh)
{
  // one-time agent acquire: emits buffer_inv sc1 -> kills stale L1/L2 lines
  // from previous graph replays / poison-memset. Required for fresh-mode
  // plain consumer loads; harmless otherwise.
  __builtin_amdgcn_fence(__ATOMIC_ACQUIRE, "agent");

  extern __shared__ char lds[];
  _Float16* whh_lds = (_Float16*)lds;              // 131072 B, frag layout [ks][nt][lane][8]
  _Float16* buf0    = (_Float16*)(lds + 131072);   // 8192 B partial-sum frags (waves 0+2)
  _Float16* buf1    = (_Float16*)(lds + 139264);   // 8192 B partial-sum frags (waves 1+3)

  const int l   = blockIdx.x >> 6;
  const int wg  = blockIdx.x & 63;
  const int tid = threadIdx.x;
  const int wave = tid >> 6;
  const int lane = tid & 63;

  const _Float16* wpack_hh = (const _Float16*)ws + (size_t)(l*64 + wg)*65536;
  const _Float16* wpack_ih = (l > 0)
      ? (const _Float16*)(ws + WPACK_HH_SZ) + (size_t)((l-1)*64 + wg)*65536
      : wpack_hh;  // unused for l==0
  _Float16* hring = (_Float16*)(ws + HRING_OFF);
  int* cnt  = (int*)(ws + HRING_OFF + ring_bytes(nslot));   // per-producer flags
  int* cnt2 = cnt + CNT_INTS;                               // fallback backpressure (atomic)

  // stage w_hh slice into LDS (one-time; wpack is immutable during this kernel)
  {
    const uint4* src = (const uint4*)wpack_hh;
    uint4* dst = (uint4*)whh_lds;
    for (int i = tid; i < 8192; i += 256) dst[i] = src[i];
  }

  // elementwise ownership: thread -> (batch b_ew, 4 consecutive hidden units u0..u0+3)
  const int b_ew = tid >> 2;
  const int u0   = (tid & 3) * 4;
  float cst[4] = {0.f, 0.f, 0.f, 0.f};
  float bias[4][4];            // [item][gate]
  float wx0[4][4], wx1[4][4];  // layer-0 input weights (K=2 handled in VALU)
  #pragma unroll
  for (int ii = 0; ii < 4; ii++) {
    #pragma unroll
    for (int g = 0; g < 4; g++) {
      int row = g*1024 + wg*16 + u0 + ii;
      bias[ii][g] = bih[l*4096 + row] + bhh[l*4096 + row];
      if (l == 0) { wx0[ii][g] = wih0[row*2]; wx1[ii][g] = wih0[row*2 + 1]; }
      else        { wx0[ii][g] = 0.f;         wx1[ii][g] = 0.f; }
    }
  }
  __syncthreads();

  const int m_row = lane & 15, quad = lane >> 4;

  for (int s = 1; s <= T; s++) {
    // wave-parallel waits: lane i spins on producer i's flag (64 independent
    // 64B lines; no RMW anywhere). Wave 0: own layer at >= s-1 (lockstep +
    // own h). Wave 1: layer below at >= s (input). tid 128: fallback ring
    // backpressure (atomic path, unused in fresh mode).
    if (wave == 0) {
      wait_ge(cnt + fidx(l, lane), s - 1);
    } else if (wave == 1) {
      if (l > 0) wait_ge(cnt + fidx(l - 1, lane), s);
    } else if (tid == 128) {
      if (!fresh && l < 3 && s > RINGN) wait_eq64(&cnt2[cidx(l, s-RINGN)]);
    }
    __syncthreads();

    // A source: for l>0 waves 0-1 consume h_below[s] (with w_ih), waves 2-3 h_own[s-1] (w_hh)
    const _Float16* asrc = (l > 0 && wave < 2)
        ? hring + ((size_t)(l-1)*nslot + aslot(s,   fresh))*SLOT_ELEMS
        : hring + ((size_t)l*nslot     + aslot(s-1, fresh))*SLOT_ELEMS;

    f32x4 acc[4][4];
    #pragma unroll
    for (int mt = 0; mt < 4; mt++)
      #pragma unroll
      for (int nt = 0; nt < 4; nt++) acc[mt][nt] = (f32x4){0.f, 0.f, 0.f, 0.f};

    auto kbody = [&](int ks, bool from_lds, bool plain) {
      const int kb = ks*32 + quad*8;
      f16x8 a[4], bb[4];
      #pragma unroll
      for (int mt = 0; mt < 4; mt++) {
        const _Float16* ap = asrc + (size_t)(mt*16 + m_row)*1024 + kb;
        a[mt] = plain ? *(const f16x8*)ap : load_h8_sc(ap);
      }
      if (from_lds) {
        #pragma unroll
        for (int nt = 0; nt < 4; nt++)
          bb[nt] = *(const f16x8*)(whh_lds + ((ks*4 + nt)*64 + lane)*8);
      } else {
        #pragma unroll
        for (int nt = 0; nt < 4; nt++)
          bb[nt] = *(const f16x8*)(wpack_ih + ((size_t)(ks*4 + nt)*64 + lane)*8);
      }
      #pragma unroll
      for (int mt = 0; mt < 4; mt++)
        #pragma unroll
        for (int nt = 0; nt < 4; nt++)
          acc[mt][nt] = __builtin_amdgcn_mfma_f32_16x16x32_f16(a[mt], bb[nt], acc[mt][nt], 0, 0, 0);
    };

    if (fresh) {
      if (l == 0) {
        #pragma unroll 4
        for (int i = 0; i < 8; i++) kbody(wave*8 + i, true, true);
      } else if (wave < 2) {
        #pragma unroll 4
        for (int i = 0; i < 16; i++) kbody(wave*16 + i, false, true);
      } else {
        #pragma unroll 4
        for (int i = 0; i < 16; i++) kbody((wave-2)*16 + i, true, true);
      }
    } else {
      if (l == 0) {
        #pragma unroll 2
        for (int i = 0; i < 8; i++) kbody(wave*8 + i, true, false);
      } else if (wave < 2) {
        #pragma unroll 2
        for (int i = 0; i < 16; i++) kbody(wave*16 + i, false, false);
      } else {
        #pragma unroll 2
        for (int i = 0; i < 16; i++) kbody((wave-2)*16 + i, true, false);
      }
    }

    // combine 4 wave-partials -> buf0 (w0+w2), buf1 (w1+w3), fp16 frags
    _Float16* mybuf = ((wave & 1) == 0) ? buf0 : buf1;
    if (wave >= 2) {
      #pragma unroll
      for (int mt = 0; mt < 4; mt++)
        #pragma unroll
        for (int nt = 0; nt < 4; nt++) {
          f16x4 v;
          #pragma unroll
          for (int e = 0; e < 4; e++) v[e] = (_Float16)acc[mt][nt][e];
          *(f16x4*)(mybuf + ((mt*4 + nt)*64 + lane)*4) = v;
        }
    }
    __syncthreads();   // drains vmcnt: all h reads physically complete
    if (wave < 2) {
      #pragma unroll
      for (int mt = 0; mt < 4; mt++)
        #pragma unroll
        for (int nt = 0; nt < 4; nt++) {
          f16x4 p = *(f16x4*)(mybuf + ((mt*4 + nt)*64 + lane)*4);
          f16x4 v;
          #pragma unroll
          for (int e = 0; e < 4; e++) v[e] = (_Float16)(acc[mt][nt][e] + (float)p[e]);
          *(f16x4*)(mybuf + ((mt*4 + nt)*64 + lane)*4) = v;
        }
    }
    // ring backpressure signal only needed when slots are reused (fallback mode)
    if (!fresh && tid == 0 && l > 0)
      __hip_atomic_fetch_add(&cnt2[cidx(l-1, s)], 1, __ATOMIC_RELAXED, __HIP_MEMORY_SCOPE_AGENT);
    __syncthreads();

    // elementwise gates -> c,h  (fp32)
    {
      const int mt = b_ew >> 4, q = (b_ew & 15) >> 2, reg = b_ew & 3;
      float xs0 = 0.f, xs1 = 0.f;
      if (l == 0) {
        xs0 = x[((size_t)b_ew*T + (s-1))*2];
        xs1 = x[((size_t)b_ew*T + (s-1))*2 + 1];
      }
      f16x4 hv;
      #pragma unroll
      for (int ii = 0; ii < 4; ii++) {
        const int u = u0 + ii;
        float pre[4];
        #pragma unroll
        for (int g = 0; g < 4; g++) {
          int idx = ((mt*4 + g)*64 + (u + 16*q))*4 + reg;
          pre[g] = (float)buf0[idx] + (float)buf1[idx] + bias[ii][g]
                 + wx0[ii][g]*xs0 + wx1[ii][g]*xs1;
        }
        float ig = 1.f/(1.f + __expf(-pre[0]));
        float fg = 1.f/(1.f + __expf(-pre[1]));
        float gg = 2.f/(1.f + __expf(-2.f*pre[2])) - 1.f;
        float og = 1.f/(1.f + __expf(-pre[3]));
        float c  = fg*cst[ii] + ig*gg;
        cst[ii] = c;
        float th = 2.f/(1.f + __expf(-2.f*c)) - 1.f;
        hv[ii] = (_Float16)(og*th);
      }
      _Float16* hdst = hring + ((size_t)l*nslot + aslot(s, fresh))*SLOT_ELEMS
                     + (size_t)b_ew*1024 + wg*16 + u0;
      union { f16x4 v; unsigned long long u; } cv; cv.v = hv;
      // sc write-through: IF$ (coherence point) holds the authoritative copy
      __hip_atomic_store((unsigned long long*)hdst, cv.u,
                         __ATOMIC_RELAXED, __HIP_MEMORY_SCOPE_AGENT);
    }
    __syncthreads();   // drains vmcnt: h stores acked at coherence point before flag
    if (tid == 0)      // plain sc store publish: no RMW, per-producer line
      __hip_atomic_store(cnt + fidx(l, wg), s,
                         __ATOMIC_RELAXED, __HIP_MEMORY_SCOPE_AGENT);
  }
}

__global__ void fc_kernel(const char* __restrict__ ws,
                          const float* __restrict__ fcw,
                          const float* __restrict__ fcb,
                          float* __restrict__ out, int nslot, int fresh)
{
  const _Float16* h3 = (const _Float16*)(ws + HRING_OFF)
                     + ((size_t)3*nslot + aslot(T, fresh))*SLOT_ELEMS;  // layer 3, t=256
  __shared__ float red[256];
  const int tid = threadIdx.x;
  const int b = tid >> 2, p = tid & 3;
  float sum = 0.f;
  for (int j = p*256; j < p*256 + 256; j++)
    sum += fcw[j] * (float)h3[(size_t)b*1024 + j];
  red[tid] = sum;
  __syncthreads();
  if (p == 0)
    out[b] = red[tid] + red[tid+1] + red[tid+2] + red[tid+3] + fcb[0];
}

extern "C" void kernel_launch(void* const* d_in, const int* in_sizes, int n_in,
                              void* d_out, int out_size, void* d_ws, size_t ws_size,
                              hipStream_t stream)
{
  const float* x    = (const float*)d_in[0];
  const float* wih0 = (const float*)d_in[1];
  const float* wihr = (const float*)d_in[2];
  const float* whh  = (const float*)d_in[3];
  const float* bih  = (const float*)d_in[4];
  const float* bhh  = (const float*)d_in[5];
  const float* fcw  = (const float*)d_in[6];
  const float* fcb  = (const float*)d_in[7];
  float* out = (float*)d_out;
  char* ws = (char*)d_ws;
  (void)in_sizes; (void)n_in; (void)out_size;

  const unsigned long long ws_big   = HRING_OFF + ring_bytes(257) + 2*CNT_BYTES; // ~193.6 MB
  const unsigned long long ws_small = HRING_OFF + ring_bytes(8)   + 2*CNT_BYTES; // ~63 MB
  if (ws_size < ws_small) return;
  const int fresh = (ws_size >= ws_big) ? 1 : 0;
  const int nslot = fresh ? 257 : 8;

  // opt-in to 147456 B dynamic LDS (host-side, idempotent, capture-safe)
  hipFuncSetAttribute(reinterpret_cast<const void*>(lstm_main),
                      hipFuncAttributeMaxDynamicSharedMemorySize, 147456);

  hipMemsetAsync(ws + HRING_OFF + ring_bytes(nslot), 0, (size_t)(2*CNT_BYTES), stream);
  pack_kernel<<<512, 256, 0, stream>>>(wihr, whh, ws, nslot);
  lstm_main<<<256, 256, 147456, stream>>>(x, wih0, bih, bhh, ws, nslot, fresh);
  fc_kernel<<<1, 256, 0, stream>>>(ws, fcw, fcb, out, nslot, fresh);
}

// Round 7
// 3799.713 us; speedup vs baseline: 1.6674x; 1.0147x over previous
//
#include <hip/hip_runtime.h>
#include <hip/hip_bf16.h>
#include <hip/hip_fp16.h>

// ---------------------------------------------------------------------------
// 4-layer LSTM (H=1024, B=64, T=256) + FC, persistent pipelined kernel.
// R11: R10 (per-producer flags, unroll-4 GEMM, specialized waves, LDS w_hh,
//      f16 partials, fresh bit-reversed ring) with the wait phase rebuilt as
//      PER-WAVE DATAFLOW WAITS in fresh mode:
//        wave 0 (ih k 0-511):   polls below-layer flags [0..31]  >= s
//        wave 1 (ih k 512-1023):polls below-layer flags [32..63] >= s
//        wave 2 (hh k 0-511):   polls own-layer flags  [0..31]  >= s-1
//        wave 3 (hh k 512-1023):polls own-layer flags  [32..63] >= s-1
//        (l==0: wave w polls own flags [16w..16w+15] >= s-1)
//      and NO pre-GEMM __syncthreads: each wave starts its GEMM as soon as
//      ITS producers published. Previously every step paid max over 128
//      producer events + a 4-wave barrier; the true dependency is 32.
//      The remaining 3 barriers (post-partial, post-add, post-EW-drain)
//      still confine waves to one step region -> buf reuse stays race-free.
//      Fallback (!fresh) path keeps the old wait+barrier structure.
// ---------------------------------------------------------------------------

#define H      1024
#define BATCH  64
#define T      256
#define RINGN  8

typedef _Float16 f16x8 __attribute__((ext_vector_type(8)));
typedef _Float16 f16x4 __attribute__((ext_vector_type(4)));
typedef float    f32x4 __attribute__((ext_vector_type(4)));

// ws layout (bytes)
#define WPACK_HH_SZ  (4ull*64*32*4*64*8*2)           // 33554432: [l][wg][ks][nt][lane][8] f16
#define WPACK_IH_SZ  (3ull*64*32*4*64*8*2)           // 25165824
#define HRING_OFF    (WPACK_HH_SZ + WPACK_IH_SZ)     // 58720256
#define SLOT_ELEMS   65536                           // per (l,slot): 64 batch x 1024 units f16
#define SLOT_BYTES   131072ull
#define CNT_INTS     (4*257*16)                      // flag/cnt2 region, 64B-padded entries
#define CNT_BYTES    ((unsigned long long)CNT_INTS*4)

__host__ __device__ __forceinline__ unsigned long long ring_bytes(int nslot) {
  return 4ull*(unsigned)nslot*SLOT_BYTES;
}
__device__ __forceinline__ int cidx(int l, int s) { return (l*257 + s)*16; }
// per-producer flag index: one 64B line per (layer, wg-block)
__device__ __forceinline__ int fidx(int l, int w) { return (l*64 + w)*16; }

// fresh mode: bit-reversed slot index kills any sequential-prefetch adjacency
__device__ __forceinline__ int aslot(int s, int fresh) {
  if (!fresh) return s & 7;
  return (s >= 256) ? 256 : (int)(__brev((unsigned)s) >> 24);
}

__device__ __forceinline__ void wait_eq64(int* p) {
  int it = 0;
  while (__hip_atomic_load(p, __ATOMIC_RELAXED, __HIP_MEMORY_SCOPE_AGENT) < 64) {
    __builtin_amdgcn_s_sleep(1);
    if (++it > 100000000) break;   // failsafe: never hang the harness
  }
}

// per-lane spin: lane waits until *p >= tgt (monotone flag)
__device__ __forceinline__ void wait_ge(const int* p, int tgt) {
  int it = 0;
  while (__hip_atomic_load(p, __ATOMIC_RELAXED, __HIP_MEMORY_SCOPE_AGENT) < tgt) {
    __builtin_amdgcn_s_sleep(1);
    if (++it > 100000000) break;   // failsafe: never hang the harness
  }
}

__device__ __forceinline__ f16x8 load_h8_sc(const _Float16* p) {
  const unsigned long long* q = (const unsigned long long*)p;
  unsigned long long lo = __hip_atomic_load(q,     __ATOMIC_RELAXED, __HIP_MEMORY_SCOPE_AGENT);
  unsigned long long hi = __hip_atomic_load(q + 1, __ATOMIC_RELAXED, __HIP_MEMORY_SCOPE_AGENT);
  union { unsigned long long u[2]; f16x8 v; } c;
  c.u[0] = lo; c.u[1] = hi;
  return c.v;
}

// --- pack weights fp32 -> fp16 MFMA-fragment layout; zero h ring slot 0; preset flags=0
__global__ void pack_kernel(const float* __restrict__ w_ih_rest,
                            const float* __restrict__ w_hh,
                            char* __restrict__ ws, int nslot)
{
  const long long NS_HH = 4ll*64*32*4*64;   // 2097152
  const long long NS_IH = 3ll*64*32*4*64;   // 1572864
  const long long NS_HZ = 4ll*8192;         // uint4 slots to zero slot-0 of each layer ring
  const long long NTOT  = NS_HH + NS_IH + NS_HZ + 256;
  _Float16* whh_dst = (_Float16*)ws;
  _Float16* wih_dst = (_Float16*)(ws + WPACK_HH_SZ);
  int* cnt = (int*)(ws + HRING_OFF + ring_bytes(nslot));
  for (long long i = blockIdx.x*(long long)blockDim.x + threadIdx.x; i < NTOT;
       i += (long long)gridDim.x*blockDim.x) {
    if (i < NS_HH + NS_IH) {
      const bool is_hh = (i < NS_HH);
      long long slot = is_hh ? i : (i - NS_HH);
      long long j = slot;
      int lane = (int)(j & 63); j >>= 6;
      int nt   = (int)(j & 3);  j >>= 2;
      int ks   = (int)(j & 31); j >>= 5;
      int wg   = (int)(j & 63); j >>= 6;
      int l    = (int)j;
      int row = nt*1024 + wg*16 + (lane & 15);      // global gate row (nt = gate: i,f,g,o)
      int col = ks*32 + (lane >> 4)*8;
      const float* src = (is_hh ? w_hh : w_ih_rest) + ((long long)l*4096 + row)*1024 + col;
      f16x8 v;
      #pragma unroll
      for (int e = 0; e < 8; e++) v[e] = (_Float16)src[e];
      *(f16x8*)((is_hh ? whh_dst : wih_dst) + slot*8) = v;
    } else if (i < NS_HH + NS_IH + NS_HZ) {
      long long j = i - (NS_HH + NS_IH);
      long long l = j >> 13;            // /8192
      long long off = j & 8191;
      uint4 z = make_uint4(0,0,0,0);
      ((uint4*)(ws + HRING_OFF))[(l*(long long)nslot)*8192 + off] = z;  // zero h[l][slot0]
    } else {
      int k = (int)(i - (NS_HH + NS_IH + NS_HZ));   // 0..255 = l*64+wg
      cnt[k*16] = 0;                                // flag: "step 0 published"
    }
  }
}

__global__ __launch_bounds__(256, 1) void lstm_main(
    const float* __restrict__ x,
    const float* __restrict__ wih0,
    const float* __restrict__ bih,
    const float* __restrict__ bhh,
    char* __restrict__ ws, int nslot, int fresh)
{
  // one-time agent acquire: emits buffer_inv sc1 -> kills stale L1/L2 lines
  // from previous graph replays / poison-memset. Required for fresh-mode
  // plain consumer loads; harmless otherwise.
  __builtin_amdgcn_fence(__ATOMIC_ACQUIRE, "agent");

  extern __shared__ char lds[];
  _Float16* whh_lds = (_Float16*)lds;              // 131072 B, frag layout [ks][nt][lane][8]
  _Float16* buf0    = (_Float16*)(lds + 131072);   // 8192 B partial-sum frags (waves 0+2)
  _Float16* buf1    = (_Float16*)(lds + 139264);   // 8192 B partial-sum frags (waves 1+3)

  const int l   = blockIdx.x >> 6;
  const int wg  = blockIdx.x & 63;
  const int tid = threadIdx.x;
  const int wave = tid >> 6;
  const int lane = tid & 63;

  const _Float16* wpack_hh = (const _Float16*)ws + (size_t)(l*64 + wg)*65536;
  const _Float16* wpack_ih = (l > 0)
      ? (const _Float16*)(ws + WPACK_HH_SZ) + (size_t)((l-1)*64 + wg)*65536
      : wpack_hh;  // unused for l==0
  _Float16* hring = (_Float16*)(ws + HRING_OFF);
  int* cnt  = (int*)(ws + HRING_OFF + ring_bytes(nslot));   // per-producer flags
  int* cnt2 = cnt + CNT_INTS;                               // fallback backpressure (atomic)

  // stage w_hh slice into LDS (one-time; wpack is immutable during this kernel)
  {
    const uint4* src = (const uint4*)wpack_hh;
    uint4* dst = (uint4*)whh_lds;
    for (int i = tid; i < 8192; i += 256) dst[i] = src[i];
  }

  // elementwise ownership: thread -> (batch b_ew, 4 consecutive hidden units u0..u0+3)
  const int b_ew = tid >> 2;
  const int u0   = (tid & 3) * 4;
  float cst[4] = {0.f, 0.f, 0.f, 0.f};
  float bias[4][4];            // [item][gate]
  float wx0[4][4], wx1[4][4];  // layer-0 input weights (K=2 handled in VALU)
  #pragma unroll
  for (int ii = 0; ii < 4; ii++) {
    #pragma unroll
    for (int g = 0; g < 4; g++) {
      int row = g*1024 + wg*16 + u0 + ii;
      bias[ii][g] = bih[l*4096 + row] + bhh[l*4096 + row];
      if (l == 0) { wx0[ii][g] = wih0[row*2]; wx1[ii][g] = wih0[row*2 + 1]; }
      else        { wx0[ii][g] = 0.f;         wx1[ii][g] = 0.f; }
    }
  }
  __syncthreads();

  const int m_row = lane & 15, quad = lane >> 4;

  for (int s = 1; s <= T; s++) {
    if (fresh) {
      // per-wave dataflow waits; NO pre-GEMM barrier. Each wave polls only
      // the 32 (16 for l==0) producer chunks its GEMM half actually reads.
      if (l == 0) {
        if (lane < 16) wait_ge(cnt + fidx(0, wave*16 + lane), s - 1);
      } else {
        if (wave == 0)      { if (lane < 32) wait_ge(cnt + fidx(l-1, lane),      s); }
        else if (wave == 1) { if (lane < 32) wait_ge(cnt + fidx(l-1, 32 + lane), s); }
        else if (wave == 2) { if (lane < 32) wait_ge(cnt + fidx(l,   lane),      s - 1); }
        else                { if (lane < 32) wait_ge(cnt + fidx(l,   32 + lane), s - 1); }
      }
    } else {
      // fallback: old wide waits + barrier (ring-reuse mode)
      if (wave == 0) {
        wait_ge(cnt + fidx(l, lane), s - 1);
      } else if (wave == 1) {
        if (l > 0) wait_ge(cnt + fidx(l - 1, lane), s);
      } else if (tid == 128) {
        if (l < 3 && s > RINGN) wait_eq64(&cnt2[cidx(l, s-RINGN)]);
      }
      __syncthreads();
    }

    // A source: for l>0 waves 0-1 consume h_below[s] (with w_ih), waves 2-3 h_own[s-1] (w_hh)
    const _Float16* asrc = (l > 0 && wave < 2)
        ? hring + ((size_t)(l-1)*nslot + aslot(s,   fresh))*SLOT_ELEMS
        : hring + ((size_t)l*nslot     + aslot(s-1, fresh))*SLOT_ELEMS;

    f32x4 acc[4][4];
    #pragma unroll
    for (int mt = 0; mt < 4; mt++)
      #pragma unroll
      for (int nt = 0; nt < 4; nt++) acc[mt][nt] = (f32x4){0.f, 0.f, 0.f, 0.f};

    auto kbody = [&](int ks, bool from_lds, bool plain) {
      const int kb = ks*32 + quad*8;
      f16x8 a[4], bb[4];
      #pragma unroll
      for (int mt = 0; mt < 4; mt++) {
        const _Float16* ap = asrc + (size_t)(mt*16 + m_row)*1024 + kb;
        a[mt] = plain ? *(const f16x8*)ap : load_h8_sc(ap);
      }
      if (from_lds) {
        #pragma unroll
        for (int nt = 0; nt < 4; nt++)
          bb[nt] = *(const f16x8*)(whh_lds + ((ks*4 + nt)*64 + lane)*8);
      } else {
        #pragma unroll
        for (int nt = 0; nt < 4; nt++)
          bb[nt] = *(const f16x8*)(wpack_ih + ((size_t)(ks*4 + nt)*64 + lane)*8);
      }
      #pragma unroll
      for (int mt = 0; mt < 4; mt++)
        #pragma unroll
        for (int nt = 0; nt < 4; nt++)
          acc[mt][nt] = __builtin_amdgcn_mfma_f32_16x16x32_f16(a[mt], bb[nt], acc[mt][nt], 0, 0, 0);
    };

    if (fresh) {
      if (l == 0) {
        #pragma unroll 4
        for (int i = 0; i < 8; i++) kbody(wave*8 + i, true, true);
      } else if (wave < 2) {
        #pragma unroll 4
        for (int i = 0; i < 16; i++) kbody(wave*16 + i, false, true);
      } else {
        #pragma unroll 4
        for (int i = 0; i < 16; i++) kbody((wave-2)*16 + i, true, true);
      }
    } else {
      if (l == 0) {
        #pragma unroll 2
        for (int i = 0; i < 8; i++) kbody(wave*8 + i, true, false);
      } else if (wave < 2) {
        #pragma unroll 2
        for (int i = 0; i < 16; i++) kbody(wave*16 + i, false, false);
      } else {
        #pragma unroll 2
        for (int i = 0; i < 16; i++) kbody((wave-2)*16 + i, true, false);
      }
    }

    // combine 4 wave-partials -> buf0 (w0+w2), buf1 (w1+w3), fp16 frags
    _Float16* mybuf = ((wave & 1) == 0) ? buf0 : buf1;
    if (wave >= 2) {
      #pragma unroll
      for (int mt = 0; mt < 4; mt++)
        #pragma unroll
        for (int nt = 0; nt < 4; nt++) {
          f16x4 v;
          #pragma unroll
          for (int e = 0; e < 4; e++) v[e] = (_Float16)acc[mt][nt][e];
          *(f16x4*)(mybuf + ((mt*4 + nt)*64 + lane)*4) = v;
        }
    }
    __syncthreads();   // bar1: partials visible; also drains h reads
    if (wave < 2) {
      #pragma unroll
      for (int mt = 0; mt < 4; mt++)
        #pragma unroll
        for (int nt = 0; nt < 4; nt++) {
          f16x4 p = *(f16x4*)(mybuf + ((mt*4 + nt)*64 + lane)*4);
          f16x4 v;
          #pragma unroll
          for (int e = 0; e < 4; e++) v[e] = (_Float16)(acc[mt][nt][e] + (float)p[e]);
          *(f16x4*)(mybuf + ((mt*4 + nt)*64 + lane)*4) = v;
        }
    }
    // ring backpressure signal only needed when slots are reused (fallback mode)
    if (!fresh && tid == 0 && l > 0)
      __hip_atomic_fetch_add(&cnt2[cidx(l-1, s)], 1, __ATOMIC_RELAXED, __HIP_MEMORY_SCOPE_AGENT);
    __syncthreads();   // bar2: summed partials visible to all

    // elementwise gates -> c,h  (fp32)
    {
      const int mt = b_ew >> 4, q = (b_ew & 15) >> 2, reg = b_ew & 3;
      float xs0 = 0.f, xs1 = 0.f;
      if (l == 0) {
        xs0 = x[((size_t)b_ew*T + (s-1))*2];
        xs1 = x[((size_t)b_ew*T + (s-1))*2 + 1];
      }
      f16x4 hv;
      #pragma unroll
      for (int ii = 0; ii < 4; ii++) {
        const int u = u0 + ii;
        float pre[4];
        #pragma unroll
        for (int g = 0; g < 4; g++) {
          int idx = ((mt*4 + g)*64 + (u + 16*q))*4 + reg;
          pre[g] = (float)buf0[idx] + (float)buf1[idx] + bias[ii][g]
                 + wx0[ii][g]*xs0 + wx1[ii][g]*xs1;
        }
        float ig = 1.f/(1.f + __expf(-pre[0]));
        float fg = 1.f/(1.f + __expf(-pre[1]));
        float gg = 2.f/(1.f + __expf(-2.f*pre[2])) - 1.f;
        float og = 1.f/(1.f + __expf(-pre[3]));
        float c  = fg*cst[ii] + ig*gg;
        cst[ii] = c;
        float th = 2.f/(1.f + __expf(-2.f*c)) - 1.f;
        hv[ii] = (_Float16)(og*th);
      }
      _Float16* hdst = hring + ((size_t)l*nslot + aslot(s, fresh))*SLOT_ELEMS
                     + (size_t)b_ew*1024 + wg*16 + u0;
      union { f16x4 v; unsigned long long u; } cv; cv.v = hv;
      // sc write-through: IF$ (coherence point) holds the authoritative copy
      __hip_atomic_store((unsigned long long*)hdst, cv.u,
                         __ATOMIC_RELAXED, __HIP_MEMORY_SCOPE_AGENT);
    }
    __syncthreads();   // bar3: h stores acked at coherence point before flag
    if (tid == 0)      // plain sc store publish: no RMW, per-producer line
      __hip_atomic_store(cnt + fidx(l, wg), s,
                         __ATOMIC_RELAXED, __HIP_MEMORY_SCOPE_AGENT);
  }
}

__global__ void fc_kernel(const char* __restrict__ ws,
                          const float* __restrict__ fcw,
                          const float* __restrict__ fcb,
                          float* __restrict__ out, int nslot, int fresh)
{
  const _Float16* h3 = (const _Float16*)(ws + HRING_OFF)
                     + ((size_t)3*nslot + aslot(T, fresh))*SLOT_ELEMS;  // layer 3, t=256
  __shared__ float red[256];
  const int tid = threadIdx.x;
  const int b = tid >> 2, p = tid & 3;
  float sum = 0.f;
  for (int j = p*256; j < p*256 + 256; j++)
    sum += fcw[j] * (float)h3[(size_t)b*1024 + j];
  red[tid] = sum;
  __syncthreads();
  if (p == 0)
    out[b] = red[tid] + red[tid+1] + red[tid+2] + red[tid+3] + fcb[0];
}

extern "C" void kernel_launch(void* const* d_in, const int* in_sizes, int n_in,
                              void* d_out, int out_size, void* d_ws, size_t ws_size,
                              hipStream_t stream)
{
  const float* x    = (const float*)d_in[0];
  const float* wih0 = (const float*)d_in[1];
  const float* wihr = (const float*)d_in[2];
  const float* whh  = (const float*)d_in[3];
  const float* bih  = (const float*)d_in[4];
  const float* bhh  = (const float*)d_in[5];
  const float* fcw  = (const float*)d_in[6];
  const float* fcb  = (const float*)d_in[7];
  float* out = (float*)d_out;
  char* ws = (char*)d_ws;
  (void)in_sizes; (void)n_in; (void)out_size;

  const unsigned long long ws_big   = HRING_OFF + ring_bytes(257) + 2*CNT_BYTES; // ~193.6 MB
  const unsigned long long ws_small = HRING_OFF + ring_bytes(8)   + 2*CNT_BYTES; // ~63 MB
  if (ws_size < ws_small) return;
  const int fresh = (ws_size >= ws_big) ? 1 : 0;
  const int nslot = fresh ? 257 : 8;

  // opt-in to 147456 B dynamic LDS (host-side, idempotent, capture-safe)
  hipFuncSetAttribute(reinterpret_cast<const void*>(lstm_main),
                      hipFuncAttributeMaxDynamicSharedMemorySize, 147456);

  hipMemsetAsync(ws + HRING_OFF + ring_bytes(nslot), 0, (size_t)(2*CNT_BYTES), stream);
  pack_kernel<<<512, 256, 0, stream>>>(wihr, whh, ws, nslot);
  lstm_main<<<256, 256, 147456, stream>>>(x, wih0, bih, bhh, ws, nslot, fresh);
  fc_kernel<<<1, 256, 0, stream>>>(ws, fcw, fcb, out, nslot, fresh);
}

// Round 8
// 3422.560 us; speedup vs baseline: 1.8511x; 1.1102x over previous
//
#include <hip/hip_runtime.h>
#include <hip/hip_bf16.h>
#include <hip/hip_fp16.h>

// ---------------------------------------------------------------------------
// 4-layer LSTM (H=1024, B=64, T=256) + FC, persistent pipelined kernel.
// R12: R11 (dataflow waits, unroll-4, specialized waves, fresh ring) with the
//      EPILOGUE COLLAPSED: 4 per-wave partial buffers, no add-pass, and only
//      TWO barriers per step (was three + an LDS read-modify-write pass):
//        wait -> GEMM -> partial write -> bar1 -> EW(sum 4 bufs) -> h store
//        -> bar2 -> publish
//      LDS: w_hh ks 0..27 staged (114688 B) + 4 x 8192 B partials = 147456 B
//      (unchanged opt-in). w_hh ks 28..31 stream from global wpack_hh
//      (immutable, IF$-resident; +16 KB/block-step).
//      Rationale: R7-R11 bounded weights/ILP/atomics/fan-in each at <=1us;
//      the remaining ~10us/step of wait contains 3 block-wide barriers and an
//      add-pass inside the layer recurrence - this removes one barrier and
//      the add-pass. Barrier order per wave is identical every iteration
//      (2/step) -> no aliasing; buf reuse guarded by bar2(s) < pwrite(s+1).
// ---------------------------------------------------------------------------

#define H      1024
#define BATCH  64
#define T      256
#define RINGN  8

typedef _Float16 f16x8 __attribute__((ext_vector_type(8)));
typedef _Float16 f16x4 __attribute__((ext_vector_type(4)));
typedef float    f32x4 __attribute__((ext_vector_type(4)));

// ws layout (bytes)
#define WPACK_HH_SZ  (4ull*64*32*4*64*8*2)           // 33554432: [l][wg][ks][nt][lane][8] f16
#define WPACK_IH_SZ  (3ull*64*32*4*64*8*2)           // 25165824
#define HRING_OFF    (WPACK_HH_SZ + WPACK_IH_SZ)     // 58720256
#define SLOT_ELEMS   65536                           // per (l,slot): 64 batch x 1024 units f16
#define SLOT_BYTES   131072ull
#define CNT_INTS     (4*257*16)                      // flag/cnt2 region, 64B-padded entries
#define CNT_BYTES    ((unsigned long long)CNT_INTS*4)

__host__ __device__ __forceinline__ unsigned long long ring_bytes(int nslot) {
  return 4ull*(unsigned)nslot*SLOT_BYTES;
}
__device__ __forceinline__ int cidx(int l, int s) { return (l*257 + s)*16; }
// per-producer flag index: one 64B line per (layer, wg-block)
__device__ __forceinline__ int fidx(int l, int w) { return (l*64 + w)*16; }

// fresh mode: bit-reversed slot index kills any sequential-prefetch adjacency
__device__ __forceinline__ int aslot(int s, int fresh) {
  if (!fresh) return s & 7;
  return (s >= 256) ? 256 : (int)(__brev((unsigned)s) >> 24);
}

__device__ __forceinline__ void wait_eq64(int* p) {
  int it = 0;
  while (__hip_atomic_load(p, __ATOMIC_RELAXED, __HIP_MEMORY_SCOPE_AGENT) < 64) {
    __builtin_amdgcn_s_sleep(1);
    if (++it > 100000000) break;   // failsafe: never hang the harness
  }
}

// per-lane spin: lane waits until *p >= tgt (monotone flag)
__device__ __forceinline__ void wait_ge(const int* p, int tgt) {
  int it = 0;
  while (__hip_atomic_load(p, __ATOMIC_RELAXED, __HIP_MEMORY_SCOPE_AGENT) < tgt) {
    __builtin_amdgcn_s_sleep(1);
    if (++it > 100000000) break;   // failsafe: never hang the harness
  }
}

__device__ __forceinline__ f16x8 load_h8_sc(const _Float16* p) {
  const unsigned long long* q = (const unsigned long long*)p;
  unsigned long long lo = __hip_atomic_load(q,     __ATOMIC_RELAXED, __HIP_MEMORY_SCOPE_AGENT);
  unsigned long long hi = __hip_atomic_load(q + 1, __ATOMIC_RELAXED, __HIP_MEMORY_SCOPE_AGENT);
  union { unsigned long long u[2]; f16x8 v; } c;
  c.u[0] = lo; c.u[1] = hi;
  return c.v;
}

// --- pack weights fp32 -> fp16 MFMA-fragment layout; zero h ring slot 0; preset flags=0
__global__ void pack_kernel(const float* __restrict__ w_ih_rest,
                            const float* __restrict__ w_hh,
                            char* __restrict__ ws, int nslot)
{
  const long long NS_HH = 4ll*64*32*4*64;   // 2097152
  const long long NS_IH = 3ll*64*32*4*64;   // 1572864
  const long long NS_HZ = 4ll*8192;         // uint4 slots to zero slot-0 of each layer ring
  const long long NTOT  = NS_HH + NS_IH + NS_HZ + 256;
  _Float16* whh_dst = (_Float16*)ws;
  _Float16* wih_dst = (_Float16*)(ws + WPACK_HH_SZ);
  int* cnt = (int*)(ws + HRING_OFF + ring_bytes(nslot));
  for (long long i = blockIdx.x*(long long)blockDim.x + threadIdx.x; i < NTOT;
       i += (long long)gridDim.x*blockDim.x) {
    if (i < NS_HH + NS_IH) {
      const bool is_hh = (i < NS_HH);
      long long slot = is_hh ? i : (i - NS_HH);
      long long j = slot;
      int lane = (int)(j & 63); j >>= 6;
      int nt   = (int)(j & 3);  j >>= 2;
      int ks   = (int)(j & 31); j >>= 5;
      int wg   = (int)(j & 63); j >>= 6;
      int l    = (int)j;
      int row = nt*1024 + wg*16 + (lane & 15);      // global gate row (nt = gate: i,f,g,o)
      int col = ks*32 + (lane >> 4)*8;
      const float* src = (is_hh ? w_hh : w_ih_rest) + ((long long)l*4096 + row)*1024 + col;
      f16x8 v;
      #pragma unroll
      for (int e = 0; e < 8; e++) v[e] = (_Float16)src[e];
      *(f16x8*)((is_hh ? whh_dst : wih_dst) + slot*8) = v;
    } else if (i < NS_HH + NS_IH + NS_HZ) {
      long long j = i - (NS_HH + NS_IH);
      long long l = j >> 13;            // /8192
      long long off = j & 8191;
      uint4 z = make_uint4(0,0,0,0);
      ((uint4*)(ws + HRING_OFF))[(l*(long long)nslot)*8192 + off] = z;  // zero h[l][slot0]
    } else {
      int k = (int)(i - (NS_HH + NS_IH + NS_HZ));   // 0..255 = l*64+wg
      cnt[k*16] = 0;                                // flag: "step 0 published"
    }
  }
}

__global__ __launch_bounds__(256, 1) void lstm_main(
    const float* __restrict__ x,
    const float* __restrict__ wih0,
    const float* __restrict__ bih,
    const float* __restrict__ bhh,
    char* __restrict__ ws, int nslot, int fresh)
{
  // one-time agent acquire: emits buffer_inv sc1 -> kills stale L1/L2 lines
  // from previous graph replays / poison-memset. Required for fresh-mode
  // plain consumer loads; harmless otherwise.
  __builtin_amdgcn_fence(__ATOMIC_ACQUIRE, "agent");

  extern __shared__ char lds[];
  _Float16* whh_lds = (_Float16*)lds;              // 114688 B: w_hh ks 0..27, [ks][nt][lane][8]
  _Float16* bufs    = (_Float16*)(lds + 114688);   // 4 x 8192 B per-wave partial frags

  const int l   = blockIdx.x >> 6;
  const int wg  = blockIdx.x & 63;
  const int tid = threadIdx.x;
  const int wave = tid >> 6;
  const int lane = tid & 63;

  const _Float16* wpack_hh = (const _Float16*)ws + (size_t)(l*64 + wg)*65536;
  const _Float16* wpack_ih = (l > 0)
      ? (const _Float16*)(ws + WPACK_HH_SZ) + (size_t)((l-1)*64 + wg)*65536
      : wpack_hh;  // unused for l==0
  _Float16* hring = (_Float16*)(ws + HRING_OFF);
  int* cnt  = (int*)(ws + HRING_OFF + ring_bytes(nslot));   // per-producer flags
  int* cnt2 = cnt + CNT_INTS;                               // fallback backpressure (atomic)

  // stage w_hh ks 0..27 into LDS (one-time; wpack is immutable; global layout
  // is ks-major so the first 114688 B are exactly ks 0..27)
  {
    const uint4* src = (const uint4*)wpack_hh;
    uint4* dst = (uint4*)whh_lds;
    for (int i = tid; i < 7168; i += 256) dst[i] = src[i];
  }

  // elementwise ownership: thread -> (batch b_ew, 4 consecutive hidden units u0..u0+3)
  const int b_ew = tid >> 2;
  const int u0   = (tid & 3) * 4;
  float cst[4] = {0.f, 0.f, 0.f, 0.f};
  float bias[4][4];            // [item][gate]
  float wx0[4][4], wx1[4][4];  // layer-0 input weights (K=2 handled in VALU)
  #pragma unroll
  for (int ii = 0; ii < 4; ii++) {
    #pragma unroll
    for (int g = 0; g < 4; g++) {
      int row = g*1024 + wg*16 + u0 + ii;
      bias[ii][g] = bih[l*4096 + row] + bhh[l*4096 + row];
      if (l == 0) { wx0[ii][g] = wih0[row*2]; wx1[ii][g] = wih0[row*2 + 1]; }
      else        { wx0[ii][g] = 0.f;         wx1[ii][g] = 0.f; }
    }
  }
  __syncthreads();

  const int m_row = lane & 15, quad = lane >> 4;

  for (int s = 1; s <= T; s++) {
    if (fresh) {
      // per-wave dataflow waits; NO pre-GEMM barrier. Each wave polls only
      // the producer chunks its GEMM segment actually reads.
      if (l == 0) {
        if (lane < 16) wait_ge(cnt + fidx(0, wave*16 + lane), s - 1);
      } else {
        if (wave == 0)      { if (lane < 32) wait_ge(cnt + fidx(l-1, lane),      s); }
        else if (wave == 1) { if (lane < 32) wait_ge(cnt + fidx(l-1, 32 + lane), s); }
        else if (wave == 2) { if (lane < 32) wait_ge(cnt + fidx(l,   lane),      s - 1); }
        else                { if (lane < 32) wait_ge(cnt + fidx(l,   32 + lane), s - 1); }
      }
    } else {
      // fallback: wide waits + barrier (ring-reuse mode)
      if (wave == 0) {
        wait_ge(cnt + fidx(l, lane), s - 1);
      } else if (wave == 1) {
        if (l > 0) wait_ge(cnt + fidx(l - 1, lane), s);
      } else if (tid == 128) {
        if (l < 3 && s > RINGN) wait_eq64(&cnt2[cidx(l, s-RINGN)]);
      }
      __syncthreads();
    }

    // A source: for l>0 waves 0-1 consume h_below[s] (with w_ih), waves 2-3 h_own[s-1] (w_hh)
    const _Float16* asrc = (l > 0 && wave < 2)
        ? hring + ((size_t)(l-1)*nslot + aslot(s,   fresh))*SLOT_ELEMS
        : hring + ((size_t)l*nslot     + aslot(s-1, fresh))*SLOT_ELEMS;

    f32x4 acc[4][4];
    #pragma unroll
    for (int mt = 0; mt < 4; mt++)
      #pragma unroll
      for (int nt = 0; nt < 4; nt++) acc[mt][nt] = (f32x4){0.f, 0.f, 0.f, 0.f};

    // b from LDS (w_hh ks<28)
    auto kb_lds = [&](int ks, bool plain) {
      const int kb = ks*32 + quad*8;
      f16x8 a[4], bb[4];
      #pragma unroll
      for (int mt = 0; mt < 4; mt++) {
        const _Float16* ap = asrc + (size_t)(mt*16 + m_row)*1024 + kb;
        a[mt] = plain ? *(const f16x8*)ap : load_h8_sc(ap);
      }
      #pragma unroll
      for (int nt = 0; nt < 4; nt++)
        bb[nt] = *(const f16x8*)(whh_lds + ((ks*4 + nt)*64 + lane)*8);
      #pragma unroll
      for (int mt = 0; mt < 4; mt++)
        #pragma unroll
        for (int nt = 0; nt < 4; nt++)
          acc[mt][nt] = __builtin_amdgcn_mfma_f32_16x16x32_f16(a[mt], bb[nt], acc[mt][nt], 0, 0, 0);
    };
    // b from global (w_ih stream, or w_hh spill ks>=28)
    auto kb_glob = [&](int ks, const _Float16* bsrc, bool plain) {
      const int kb = ks*32 + quad*8;
      f16x8 a[4], bb[4];
      #pragma unroll
      for (int mt = 0; mt < 4; mt++) {
        const _Float16* ap = asrc + (size_t)(mt*16 + m_row)*1024 + kb;
        a[mt] = plain ? *(const f16x8*)ap : load_h8_sc(ap);
      }
      #pragma unroll
      for (int nt = 0; nt < 4; nt++)
        bb[nt] = *(const f16x8*)(bsrc + ((size_t)(ks*4 + nt)*64 + lane)*8);
      #pragma unroll
      for (int mt = 0; mt < 4; mt++)
        #pragma unroll
        for (int nt = 0; nt < 4; nt++)
          acc[mt][nt] = __builtin_amdgcn_mfma_f32_16x16x32_f16(a[mt], bb[nt], acc[mt][nt], 0, 0, 0);
    };

    const bool pl = (fresh != 0);
    if (l == 0) {
      if (wave < 3) {
        #pragma unroll 4
        for (int i = 0; i < 8; i++) kb_lds(wave*8 + i, pl);
      } else {
        #pragma unroll 4
        for (int i = 0; i < 4; i++) kb_lds(24 + i, pl);
        #pragma unroll
        for (int i = 0; i < 4; i++) kb_glob(28 + i, wpack_hh, pl);
      }
    } else if (wave < 2) {
      #pragma unroll 4
      for (int i = 0; i < 16; i++) kb_glob(wave*16 + i, wpack_ih, pl);
    } else if (wave == 2) {
      #pragma unroll 4
      for (int i = 0; i < 16; i++) kb_lds(i, pl);
    } else {
      #pragma unroll 4
      for (int i = 0; i < 12; i++) kb_lds(16 + i, pl);
      #pragma unroll
      for (int i = 0; i < 4; i++) kb_glob(28 + i, wpack_hh, pl);
    }

    // every wave writes its own partial buffer (no add pass)
    {
      _Float16* mybuf = bufs + (size_t)wave*4096;   // 8192 B each
      #pragma unroll
      for (int mt = 0; mt < 4; mt++)
        #pragma unroll
        for (int nt = 0; nt < 4; nt++) {
          f16x4 v;
          #pragma unroll
          for (int e = 0; e < 4; e++) v[e] = (_Float16)acc[mt][nt][e];
          *(f16x4*)(mybuf + ((mt*4 + nt)*64 + lane)*4) = v;
        }
    }
    // ring backpressure signal only needed when slots are reused (fallback mode)
    if (!fresh && tid == 0 && l > 0)
      __hip_atomic_fetch_add(&cnt2[cidx(l-1, s)], 1, __ATOMIC_RELAXED, __HIP_MEMORY_SCOPE_AGENT);
    __syncthreads();   // bar1: all partials visible (also: h reads complete)

    // elementwise gates -> c,h  (fp32); sums 4 partial bufs directly
    {
      const int mt = b_ew >> 4, q = (b_ew & 15) >> 2, reg = b_ew & 3;
      float xs0 = 0.f, xs1 = 0.f;
      if (l == 0) {
        xs0 = x[((size_t)b_ew*T + (s-1))*2];
        xs1 = x[((size_t)b_ew*T + (s-1))*2 + 1];
      }
      f16x4 hv;
      #pragma unroll
      for (int ii = 0; ii < 4; ii++) {
        const int u = u0 + ii;
        float pre[4];
        #pragma unroll
        for (int g = 0; g < 4; g++) {
          int idx = ((mt*4 + g)*64 + (u + 16*q))*4 + reg;
          pre[g] = (float)bufs[idx] + (float)bufs[4096 + idx]
                 + (float)bufs[8192 + idx] + (float)bufs[12288 + idx]
                 + bias[ii][g] + wx0[ii][g]*xs0 + wx1[ii][g]*xs1;
        }
        float ig = 1.f/(1.f + __expf(-pre[0]));
        float fg = 1.f/(1.f + __expf(-pre[1]));
        float gg = 2.f/(1.f + __expf(-2.f*pre[2])) - 1.f;
        float og = 1.f/(1.f + __expf(-pre[3]));
        float c  = fg*cst[ii] + ig*gg;
        cst[ii] = c;
        float th = 2.f/(1.f + __expf(-2.f*c)) - 1.f;
        hv[ii] = (_Float16)(og*th);
      }
      _Float16* hdst = hring + ((size_t)l*nslot + aslot(s, fresh))*SLOT_ELEMS
                     + (size_t)b_ew*1024 + wg*16 + u0;
      union { f16x4 v; unsigned long long u; } cv; cv.v = hv;
      // sc write-through: IF$ (coherence point) holds the authoritative copy
      __hip_atomic_store((unsigned long long*)hdst, cv.u,
                         __ATOMIC_RELAXED, __HIP_MEMORY_SCOPE_AGENT);
    }
    __syncthreads();   // bar2: h stores acked at coherence point before flag;
                       // also guards partial-buf reuse for step s+1
    if (tid == 0)      // plain sc store publish: no RMW, per-producer line
      __hip_atomic_store(cnt + fidx(l, wg), s,
                         __ATOMIC_RELAXED, __HIP_MEMORY_SCOPE_AGENT);
  }
}

__global__ void fc_kernel(const char* __restrict__ ws,
                          const float* __restrict__ fcw,
                          const float* __restrict__ fcb,
                          float* __restrict__ out, int nslot, int fresh)
{
  const _Float16* h3 = (const _Float16*)(ws + HRING_OFF)
                     + ((size_t)3*nslot + aslot(T, fresh))*SLOT_ELEMS;  // layer 3, t=256
  __shared__ float red[256];
  const int tid = threadIdx.x;
  const int b = tid >> 2, p = tid & 3;
  float sum = 0.f;
  for (int j = p*256; j < p*256 + 256; j++)
    sum += fcw[j] * (float)h3[(size_t)b*1024 + j];
  red[tid] = sum;
  __syncthreads();
  if (p == 0)
    out[b] = red[tid] + red[tid+1] + red[tid+2] + red[tid+3] + fcb[0];
}

extern "C" void kernel_launch(void* const* d_in, const int* in_sizes, int n_in,
                              void* d_out, int out_size, void* d_ws, size_t ws_size,
                              hipStream_t stream)
{
  const float* x    = (const float*)d_in[0];
  const float* wih0 = (const float*)d_in[1];
  const float* wihr = (const float*)d_in[2];
  const float* whh  = (const float*)d_in[3];
  const float* bih  = (const float*)d_in[4];
  const float* bhh  = (const float*)d_in[5];
  const float* fcw  = (const float*)d_in[6];
  const float* fcb  = (const float*)d_in[7];
  float* out = (float*)d_out;
  char* ws = (char*)d_ws;
  (void)in_sizes; (void)n_in; (void)out_size;

  const unsigned long long ws_big   = HRING_OFF + ring_bytes(257) + 2*CNT_BYTES; // ~193.6 MB
  const unsigned long long ws_small = HRING_OFF + ring_bytes(8)   + 2*CNT_BYTES; // ~63 MB
  if (ws_size < ws_small) return;
  const int fresh = (ws_size >= ws_big) ? 1 : 0;
  const int nslot = fresh ? 257 : 8;

  // opt-in to 147456 B dynamic LDS (host-side, idempotent, capture-safe)
  hipFuncSetAttribute(reinterpret_cast<const void*>(lstm_main),
                      hipFuncAttributeMaxDynamicSharedMemorySize, 147456);

  hipMemsetAsync(ws + HRING_OFF + ring_bytes(nslot), 0, (size_t)(2*CNT_BYTES), stream);
  pack_kernel<<<512, 256, 0, stream>>>(wihr, whh, ws, nslot);
  lstm_main<<<256, 256, 147456, stream>>>(x, wih0, bih, bhh, ws, nslot, fresh);
  fc_kernel<<<1, 256, 0, stream>>>(ws, fcw, fcb, out, nslot, fresh);
}